// Round 13
// baseline (869.293 us; speedup 1.0000x reference)
//
#include <hip/hip_runtime.h>
#include <hip/hip_bf16.h>
#include <cstdint>
#include <cstddef>

// Problem constants: B=32, G=512, S=128, GS=32, P=10, C=384, H=6, D=64,
// HID=1536, RED=16, tokens per batch = 513.
typedef __hip_bfloat16 bf16;
constexpr int TOK = 32 * 513;   // 16416 rows in the residual stream

typedef __attribute__((ext_vector_type(8))) short short8;
typedef __attribute__((ext_vector_type(4))) float f32x4;

__device__ __forceinline__ float bflo(unsigned u){ return __uint_as_float(u << 16); }
__device__ __forceinline__ float bfhi(unsigned u){ return __uint_as_float(u & 0xffff0000u); }
__device__ __forceinline__ float b2f(bf16 x){ return __bfloat162float(x); }
__device__ __forceinline__ bf16  f2b(float x){ return __float2bfloat16(x); }
__device__ __forceinline__ float geluf(float x){ return 0.5f*x*(1.0f + erff(x*0.70710678118654752f)); }
// Scalar decode robust to int32-vs-float32 materialization of Python scalars.
__device__ __forceinline__ float scal(const int* p){
  const int i = *p;
  if (i > -1000000 && i < 1000000) return (float)i;
  return __int_as_float(i);
}
__device__ __forceinline__ f32x4 mfma16(short8 a, short8 b, f32x4 c){
  return __builtin_amdgcn_mfma_f32_16x16x32_bf16(a, b, c, 0, 0, 0);
}
// XOR swizzle of a frag-lane index (16B LDS slot within a 64-slot tile):
// spreads bank groups using bits 3-5 so scatter writes don't serialize.
__device__ __forceinline__ int swzl(int l){ return l ^ ((l >> 3) & 7); }
// Async global->LDS 16B per lane (wave-uniform LDS base + lane*16).
__device__ __forceinline__ void gload_lds16(const bf16* g, bf16* l){
  __builtin_amdgcn_global_load_lds(
      (const __attribute__((address_space(1))) void*)g,
      (__attribute__((address_space(3))) void*)l, 16, 0, 0);
}

// ---------------------------------------------------------------------------
// Dtype detection: fp32 vs bf16 inputs.
// ---------------------------------------------------------------------------
__global__ __launch_bounds__(256) void detect_kernel(const unsigned* __restrict__ x,
                                                     int* __restrict__ flag)
{
  const int t = threadIdx.x;
  bool bad = false;
  for (int i = t; i < 2048; i += 256){
    const unsigned u = x[i];
    const float a = fabsf(bflo(u)), b = fabsf(bfhi(u));
    if (!(a < 1e6f) || !(b < 1e6f)) bad = true;
  }
  __shared__ int s;
  if (t == 0) s = 0;
  __syncthreads();
  const unsigned long long m = __ballot(bad);
  if (m != 0ull && (t & 63) == 0) atomicOr(&s, 1);
  __syncthreads();
  if (t == 0) *flag = s;
}

// ---------------------------------------------------------------------------
// Canonicalize all float inputs to bf16 (copy if already bf16).
// v2: 8 elements/thread (2x float4 load -> 16B bf16 store), scalar tail.
// ---------------------------------------------------------------------------
struct ConvArgs {
  const void* src[34];
  bf16*       dst[34];
  int         n[34];
};
__global__ __launch_bounds__(256) void convert_many(const int* __restrict__ flag, ConvArgs a)
{
  const int ii = blockIdx.y;
  const bool isf = (*flag != 0);
  const int n = a.n[ii];
  const int n8 = n >> 3;
  bf16* d = a.dst[ii];
  if (isf){
    const float4* s = (const float4*)a.src[ii];
    for (int i = blockIdx.x*256 + threadIdx.x; i < n8; i += gridDim.x*256){
      const float4 f0 = s[i*2];
      const float4 f1 = s[i*2 + 1];
      bf16 tmp[8] = {f2b(f0.x),f2b(f0.y),f2b(f0.z),f2b(f0.w),
                     f2b(f1.x),f2b(f1.y),f2b(f1.z),f2b(f1.w)};
      *(uint4*)(d + (size_t)i*8) = *(const uint4*)tmp;
    }
  } else {
    const uint4* s = (const uint4*)a.src[ii];
    for (int i = blockIdx.x*256 + threadIdx.x; i < n8; i += gridDim.x*256){
      ((uint4*)d)[i] = s[i];
    }
  }
  if (blockIdx.x == 0){
    for (int i = n8*8 + threadIdx.x; i < n; i += 256){
      d[i] = isf ? f2b(((const float*)a.src[ii])[i]) : ((const bf16*)a.src[ii])[i];
    }
  }
}

// ---------------------------------------------------------------------------
// Shuffle 6 weights W[K x N] (row-major) into MFMA B-fragment order in ONE
// dispatch (blockIdx.y = which weight; 5 launch gaps deleted).
// ---------------------------------------------------------------------------
struct ShufArgs {
  const bf16* W[6];
  bf16*       out[6];
  int         N[6];
  int         KT[6];
  int         NT[6];
};
__global__ __launch_bounds__(256) void shuffle_many(ShufArgs a)
{
  const int ii = blockIdx.y;
  const int id = blockIdx.x*256 + threadIdx.x;
  const int KT = a.KT[ii], NT = a.NT[ii], N = a.N[ii];
  if (id >= NT*KT*64) return;
  const int l  = id & 63;
  const int k0 = (id >> 6) % KT;
  const int n0 = (id >> 6) / KT;
  const bf16* W = a.W[ii];
  bf16 tmp[8];
  #pragma unroll
  for (int j = 0; j < 8; j++)
    tmp[j] = W[(size_t)(k0*32 + (l>>4)*8 + j)*N + n0*16 + (l&15)];
  *(uint4*)(a.out[ii] + (size_t)id*8) = *(const uint4*)tmp;
}

// ---------------------------------------------------------------------------
// LayerNorm: one wave per row of 384. Output bf16.
// ---------------------------------------------------------------------------
template<bool SRC_BF16>
__global__ __launch_bounds__(256) void ln_kernel(const void* __restrict__ src,
    const bf16* __restrict__ g, const bf16* __restrict__ b,
    bf16* __restrict__ out, int rows)
{
  const int wave = (blockIdx.x * blockDim.x + threadIdx.x) >> 6;
  const int lane = threadIdx.x & 63;
  if (wave >= rows) return;
  float v[6]; float s = 0.f, s2 = 0.f;
  #pragma unroll
  for (int i = 0; i < 6; i++){
    const int c = lane + 64*i;
    float x;
    if (SRC_BF16) x = b2f(((const bf16*)src)[(size_t)wave*384 + c]);
    else          x = ((const float*)src)[(size_t)wave*384 + c];
    v[i] = x; s += x; s2 += x*x;
  }
  #pragma unroll
  for (int mm = 32; mm; mm >>= 1){ s += __shfl_xor(s, mm); s2 += __shfl_xor(s2, mm); }
  const float mean = s * (1.f/384.f);
  const float rs = rsqrtf(s2 * (1.f/384.f) - mean*mean + 1e-5f);
  #pragma unroll
  for (int i = 0; i < 6; i++){
    const int c = lane + 64*i;
    out[(size_t)wave*384 + c] = f2b((v[i]-mean)*rs*b2f(g[c]) + b2f(b[c]));
  }
}

// ---------------------------------------------------------------------------
// MFMA GEMM v2: out[M,N] = A[M,K] @ W[K,N] (+bias, epilogue). A bf16 row-major,
// Bsh = W pre-shuffled to B-frag order. Block 128x128, BK=32, 256 thr (2x2
// wave grid, 4x4 16x16 tiles per wave). A staged via ASYNC global_load_lds
// width-16. EPI: 0 = bf16 out, +bias; 1 = bf16 out; 2 = bf16 gelu(+bias);
//      3 = f32 out, +bias +bf16resid
// ---------------------------------------------------------------------------
template<int EPI>
__global__ __launch_bounds__(256) void mfma_gemm(
    const bf16* __restrict__ A, const bf16* __restrict__ Bsh,
    const bf16* __restrict__ bias, const bf16* __restrict__ resid,
    void* __restrict__ outv, int M, int N, int K)
{
  __shared__ __align__(16) bf16 sA[8*64*8];   // 128x32 A tile in frag order
  const int t = threadIdx.x, lane = t & 63, w = t >> 6;
  const int l15 = lane & 15, quad = lane >> 4;
  const int wm = w & 1, wn = w >> 1;          // 2x2 wave grid
  const int m0 = blockIdx.y * 128;
  const int n0t = blockIdx.x * 8 + wn * 4;    // this wave's global n-tile base
  const int KT = K >> 5;
  f32x4 acc[4][4];
  #pragma unroll
  for (int i = 0; i < 4; i++){
    #pragma unroll
    for (int j = 0; j < 4; j++) acc[i][j] = f32x4{0.f,0.f,0.f,0.f};
  }
  // staging geometry: wave w owns m-tiles 2w and 2w+1
  const int mtA = 2*w, mtB = 2*w + 1;
  const bf16* gA = A + (size_t)(m0 + mtA*16 + l15)*K + quad*8;
  const bf16* gB = A + (size_t)(m0 + mtB*16 + l15)*K + quad*8;
  bf16* lA = sA + mtA*512;   // 64 lanes x 8 bf16 per tile
  bf16* lB = sA + mtB*512;

  for (int ks = 0; ks < KT; ks++){
    gload_lds16(gA + ks*32, lA);
    gload_lds16(gB + ks*32, lB);
    __syncthreads();   // drains vmcnt -> staged data visible
    short8 afr[4];
    #pragma unroll
    for (int i = 0; i < 4; i++)
      afr[i] = *(const short8*)(sA + (((wm*4+i)*64 + lane) << 3));
    #pragma unroll
    for (int j = 0; j < 4; j++){
      const short8 b = *(const short8*)(Bsh + ((size_t)((n0t+j)*KT + ks)*64 + lane)*8);
      #pragma unroll
      for (int i = 0; i < 4; i++) acc[i][j] = mfma16(afr[i], b, acc[i][j]);
    }
    __syncthreads();
  }
  #pragma unroll
  for (int i = 0; i < 4; i++){
    #pragma unroll
    for (int r = 0; r < 4; r++){
      const int gm = m0 + (wm*4+i)*16 + quad*4 + r;
      if (gm < M){
        #pragma unroll
        for (int j = 0; j < 4; j++){
          const int gn = (n0t+j)*16 + l15;
          float v = acc[i][j][r];
          const size_t o = (size_t)gm*N + gn;
          if (EPI == 0){ v += b2f(bias[gn]); ((bf16*)outv)[o] = f2b(v); }
          else if (EPI == 1){ ((bf16*)outv)[o] = f2b(v); }
          else if (EPI == 2){ v += b2f(bias[gn]); ((bf16*)outv)[o] = f2b(geluf(v)); }
          else { v += b2f(bias[gn]) + b2f(resid[o]); ((float*)outv)[o] = v; }
        }
      }
    }
  }
}

// ---------------------------------------------------------------------------
// Prompt QKV: (10 x 384) @ (384 x 1152) -> f32 (prompt used WITHOUT LN).
// ---------------------------------------------------------------------------
__global__ __launch_bounds__(256) void pqkv_kernel(const bf16* __restrict__ pe,
    const bf16* __restrict__ Wqkv, float* __restrict__ pq)
{
  const int n  = blockIdx.x*64 + (threadIdx.x & 63);
  const int rg = threadIdx.x >> 6;
  for (int r = rg; r < 10; r += 4){
    float s0 = 0.f, s1 = 0.f;
    for (int c = 0; c < 384; c += 2){
      s0 = fmaf(b2f(pe[(size_t)r*384+c]),   b2f(Wqkv[(size_t)c*1152 + n]),     s0);
      s1 = fmaf(b2f(pe[(size_t)r*384+c+1]), b2f(Wqkv[(size_t)(c+1)*1152 + n]), s1);
    }
    pq[(size_t)r*1152 + n] = s0 + s1;
  }
}

// ---------------------------------------------------------------------------
// Main attention v4b (MFMA flash) + prompt cross-attention fused.
// Q frags in registers; K async double-buffered via gload_lds16; V
// reg-prefetched (issue-early/write-late); s_p stride 64 (collision-free).
// ---------------------------------------------------------------------------
__global__ __launch_bounds__(256) void attn_kernel(
    const bf16* __restrict__ qkv, const float* __restrict__ pq,
    const bf16* __restrict__ gate, bf16* __restrict__ ao)
{
  __shared__ __align__(16) bf16 s_kf[2][8*64*8];  // K frags [buf][nt*2+half][lane][8]
  __shared__ __align__(16) bf16 s_vT[64*72];
  __shared__ __align__(16) bf16 s_p[4*16*64];     // P [wave][row][col], stride 64
  __shared__ __align__(16) bf16 s_pk[16*72];
  __shared__ __align__(16) bf16 s_pvT[64*40];
  const int bh = blockIdx.y;
  const int b = bh / 6, h = bh % 6;
  const int q0 = blockIdx.x * 64;
  const int t = threadIdx.x, lane = t & 63, w = t >> 6;
  const int l15 = lane & 15, quad = lane >> 4;

  // Q frags: direct global, loop-invariant (A-frag: row l15, cols quad*8..+7)
  const int qtok = q0 + w*16 + l15;
  const int qtokc = qtok < 513 ? qtok : 512;
  const bf16* qp = qkv + (size_t)(b*513 + qtokc)*1152 + h*64 + quad*8;
  const short8 qf0 = *(const short8*)qp;
  const short8 qf1 = *(const short8*)(qp + 32);

  // per-lane K staging source (row l15 of this wave's tile, clamped)
  auto issueK = [&](int kb, int buf){
    const int key = kb + w*16 + l15;
    const int keyc = key < 513 ? key : 512;
    const bf16* src = qkv + (size_t)(b*513 + keyc)*1152 + 384 + h*64 + quad*8;
    gload_lds16(src,      &s_kf[buf][((w*2 + 0)*64)*8]);
    gload_lds16(src + 32, &s_kf[buf][((w*2 + 1)*64)*8]);
  };

  // V prefetch geometry (2 keys per thread)
  const int kp = t & 31, dg = t >> 5;

  {
    const int j = t >> 4, dc = (t & 15) * 4;
    float f[4] = {0.f,0.f,0.f,0.f};
    if (j < 10){
      const float* pk = pq + (size_t)j*1152 + 384 + h*64 + dc;
      f[0]=pk[0]; f[1]=pk[1]; f[2]=pk[2]; f[3]=pk[3];
    }
    bf16 tmp[4] = {f2b(f[0]),f2b(f[1]),f2b(f[2]),f2b(f[3])};
    *(uint2*)(s_pk + j*72 + dc) = *(const uint2*)tmp;
  }
  {
    const int d = t & 63, kg = t >> 6;
    #pragma unroll
    for (int kk = 0; kk < 8; kk++){
      const int key = kg*8 + kk;
      bf16 v = f2b(0.f);
      if (key < 10) v = f2b(pq[(size_t)key*1152 + 768 + h*64 + d]);
      s_pvT[d*40 + key] = v;
    }
  }

  // prologue: prefetch V(0), issue async K(0) -> buf 0
  uint4 pv0 = {0,0,0,0}, pv1 = {0,0,0,0};
  {
    const int key0 = 2*kp;
    if (key0 < 513)
      pv0 = *(const uint4*)(qkv + (size_t)(b*513 + key0)*1152 + 768 + h*64 + dg*8);
    if (key0 + 1 < 513)
      pv1 = *(const uint4*)(qkv + (size_t)(b*513 + key0 + 1)*1152 + 768 + h*64 + dg*8);
  }
  issueK(0, 0);
  int cur = 0;

  float m_i[4], l_i[4];
  f32x4 oacc[4];
  #pragma unroll
  for (int r = 0; r < 4; r++){ m_i[r] = -30000.f; l_i[r] = 0.f; }
  #pragma unroll
  for (int nt = 0; nt < 4; nt++) oacc[nt] = f32x4{0.f,0.f,0.f,0.f};
  bf16* myp = s_p + w*16*64;

  for (int kt = 0; kt < 9; kt++){
    const int kb = kt*64;
    __syncthreads();   // drains async K(kt) into s_kf[cur]; prev PV done -> s_vT writable
    {   // write prefetched V(kt) regs -> s_vT (transpose)
      const unsigned short* a0 = (const unsigned short*)&pv0;
      const unsigned short* a1 = (const unsigned short*)&pv1;
      unsigned* vt = (unsigned*)s_vT;
      #pragma unroll
      for (int j = 0; j < 8; j++)
        vt[(dg*8 + j)*36 + kp] = (unsigned)a0[j] | ((unsigned)a1[j] << 16);
    }
    __syncthreads();   // s_vT ready

    f32x4 sreg[4];
    #pragma unroll
    for (int nt = 0; nt < 4; nt++){
      const short8 kf0 = *(const short8*)(&s_kf[cur][((nt*2 + 0)*64 + lane)*8]);
      const short8 kf1 = *(const short8*)(&s_kf[cur][((nt*2 + 1)*64 + lane)*8]);
      f32x4 acc = mfma16(qf0, kf0, f32x4{0.f,0.f,0.f,0.f});
      acc = mfma16(qf1, kf1, acc);
      const bool kvalid = (kb + nt*16 + l15) < 513;
      #pragma unroll
      for (int r = 0; r < 4; r++)
        sreg[nt][r] = kvalid ? acc[r]*0.125f : -30000.f;
    }

    // prefetch for kt+1: async K (cold buffer) + V regs; both drain/land at
    // the next top-of-loop barrier, hidden under softmax+PV below.
    if (kt < 8){
      issueK(kb + 64, cur ^ 1);
      const int key0 = kb + 64 + 2*kp;
      pv0 = {0,0,0,0}; pv1 = {0,0,0,0};
      if (key0 < 513)
        pv0 = *(const uint4*)(qkv + (size_t)(b*513 + key0)*1152 + 768 + h*64 + dg*8);
      if (key0 + 1 < 513)
        pv1 = *(const uint4*)(qkv + (size_t)(b*513 + key0 + 1)*1152 + 768 + h*64 + dg*8);
    }

    float alpha[4];
    #pragma unroll
    for (int r = 0; r < 4; r++){
      float mx = fmaxf(fmaxf(sreg[0][r], sreg[1][r]), fmaxf(sreg[2][r], sreg[3][r]));
      #pragma unroll
      for (int mm = 8; mm; mm >>= 1) mx = fmaxf(mx, __shfl_xor(mx, mm));
      const float mn = fmaxf(m_i[r], mx);
      alpha[r] = __expf(m_i[r] - mn);
      m_i[r] = mn;
      float ps = 0.f;
      #pragma unroll
      for (int nt = 0; nt < 4; nt++){
        const float p = __expf(sreg[nt][r] - mn);
        sreg[nt][r] = p; ps += p;
      }
      #pragma unroll
      for (int mm = 8; mm; mm >>= 1) ps += __shfl_xor(ps, mm);
      l_i[r] = l_i[r]*alpha[r] + ps;
    }
    #pragma unroll
    for (int nt = 0; nt < 4; nt++){
      #pragma unroll
      for (int r = 0; r < 4; r++)
        myp[(quad*4 + r)*64 + nt*16 + l15] = f2b(sreg[nt][r]);
    }
    #pragma unroll
    for (int nt = 0; nt < 4; nt++){
      #pragma unroll
      for (int r = 0; r < 4; r++) oacc[nt][r] *= alpha[r];
    }
    const short8* ap = (const short8*)(myp + l15*64);
    #pragma unroll
    for (int nt = 0; nt < 4; nt++){
      const short8* bv = (const short8*)(s_vT + (nt*16 + l15)*72);
      oacc[nt] = mfma16(ap[quad],     bv[quad],     oacc[nt]);
      oacc[nt] = mfma16(ap[4 + quad], bv[4 + quad], oacc[nt]);
    }
    cur ^= 1;
  }

  f32x4 sp;
  {
    f32x4 acc = f32x4{0.f,0.f,0.f,0.f};
    const short8* bp = (const short8*)(s_pk + l15*72);
    acc = mfma16(qf0, bp[quad],     acc);
    acc = mfma16(qf1, bp[4 + quad], acc);
    #pragma unroll
    for (int r = 0; r < 4; r++)
      sp[r] = (l15 < 10) ? acc[r]*0.125f : -30000.f;
  }
  float psr[4];
  #pragma unroll
  for (int r = 0; r < 4; r++){
    float mx = sp[r];
    #pragma unroll
    for (int mm = 8; mm; mm >>= 1) mx = fmaxf(mx, __shfl_xor(mx, mm));
    const float p = __expf(sp[r] - mx);
    float ps = p;
    #pragma unroll
    for (int mm = 8; mm; mm >>= 1) ps += __shfl_xor(ps, mm);
    psr[r] = ps;
    myp[(quad*4 + r)*64 + l15]      = f2b(p);
    myp[(quad*4 + r)*64 + 16 + l15] = f2b(0.f);
  }
  f32x4 pva[4];
  {
    const short8* ap = (const short8*)(myp + l15*64);
    #pragma unroll
    for (int nt = 0; nt < 4; nt++){
      const short8* bv = (const short8*)(s_pvT + (nt*16 + l15)*40);
      pva[nt] = mfma16(ap[quad], bv[quad], f32x4{0.f,0.f,0.f,0.f});
    }
  }

  const float gh = b2f(gate[h]);
  #pragma unroll
  for (int r = 0; r < 4; r++){
    const int tok = q0 + w*16 + quad*4 + r;
    if (tok < 513){
      const float invl = 1.f/l_i[r];
      const float gps  = gh/psr[r];
      #pragma unroll
      for (int nt = 0; nt < 4; nt++){
        const float val = oacc[nt][r]*invl + pva[nt][r]*gps;
        ao[(size_t)(b*513 + tok)*384 + h*64 + nt*16 + l15] = f2b(val);
      }
    }
  }
}

// ---------------------------------------------------------------------------
// Adapter (mid only now): one WAVE per row (4 waves / 256-thr block, no
// barriers). xres = g*(h+up+bu) + xres, FUSED LN3 -> xln3 for non-cls tokens.
// ---------------------------------------------------------------------------
__global__ __launch_bounds__(256) void adapter_mid_kernel(
    const bf16* __restrict__ src,
    const bf16* __restrict__ Wd, const bf16* __restrict__ bd,
    const bf16* __restrict__ Wu, const bf16* __restrict__ bu,
    const bf16* __restrict__ p_gate,
    const bf16* __restrict__ g3, const bf16* __restrict__ b3,
    float* __restrict__ xres, bf16* __restrict__ xln3)
{
  __shared__ float s_h[4][384];
  const int wv = threadIdx.x >> 6, lane = threadIdx.x & 63;
  const int row = blockIdx.x*4 + wv;        // grid = TOK/4 exactly
  float v[6];
  #pragma unroll
  for (int i = 0; i < 6; i++){
    const int c = lane + 64*i;
    const float x = b2f(src[(size_t)row*384 + c]);
    v[i] = x; s_h[wv][c] = x;
  }
  // same-wave LDS write->read is ordered; no barrier needed (per-wave slice)
  const int o = lane & 15, p = lane >> 4;
  float part = 0.f;
  #pragma unroll 4
  for (int j = 0; j < 96; j++)
    part = fmaf(s_h[wv][p*96 + j], b2f(Wd[(size_t)(p*96 + j)*16 + o]), part);
  part += __shfl_xor(part, 16);
  part += __shfl_xor(part, 32);
  const float y = geluf(part + b2f(bd[o]));   // lanes with equal o agree
  float up[6] = {0.f,0.f,0.f,0.f,0.f,0.f};
  #pragma unroll
  for (int o2 = 0; o2 < 16; o2++){
    const float yo = __shfl(y, o2);
    #pragma unroll
    for (int i = 0; i < 6; i++)
      up[i] = fmaf(yo, b2f(Wu[(size_t)o2*384 + lane + 64*i]), up[i]);
  }
  const float g = b2f(p_gate[0]);
  float nv[6]; float s = 0.f, s2 = 0.f;
  #pragma unroll
  for (int i = 0; i < 6; i++){
    const int c = lane + 64*i;
    const float had = v[i] + up[i] + b2f(bu[c]);
    const float nx = g*had + xres[(size_t)row*384 + c];
    xres[(size_t)row*384 + c] = nx;
    nv[i] = nx; s += nx; s2 += nx*nx;
  }
  const int boff = row % 513;
  if (boff != 0){   // fused LN3 for non-cls tokens
    #pragma unroll
    for (int mm = 32; mm; mm >>= 1){ s += __shfl_xor(s, mm); s2 += __shfl_xor(s2, mm); }
    const float mean = s * (1.f/384.f);
    const float rs = rsqrtf(s2 * (1.f/384.f) - mean*mean + 1e-5f);
    const int r3 = (row/513)*512 + boff - 1;
    #pragma unroll
    for (int i = 0; i < 6; i++){
      const int c = lane + 64*i;
      xln3[(size_t)r3*384 + c] = f2b((nv[i]-mean)*rs*b2f(g3[c]) + b2f(b3[c]));
    }
  }
}

// ---------------------------------------------------------------------------
// Final adapter for the 32 CLS tokens only (rows tok = b*513; xres untouched
// by interp for these). Wave-per-row, grid = 8 blocks x 4 waves.
// ---------------------------------------------------------------------------
__global__ __launch_bounds__(256) void cls_adapter_kernel(
    const float* __restrict__ xr,
    const bf16* __restrict__ Wd, const bf16* __restrict__ bd,
    const bf16* __restrict__ Wu, const bf16* __restrict__ bu,
    const int* __restrict__ flag, void* __restrict__ out)
{
  __shared__ float s_h[4][384];
  const int wv = threadIdx.x >> 6, lane = threadIdx.x & 63;
  const int bidx = blockIdx.x*4 + wv;       // 0..31
  const size_t row = (size_t)bidx*513;      // cls token index
  float v[6];
  #pragma unroll
  for (int i = 0; i < 6; i++){
    const int c = lane + 64*i;
    const float x = xr[row*384 + c];
    v[i] = x; s_h[wv][c] = x;
  }
  const int o = lane & 15, p = lane >> 4;
  float part = 0.f;
  #pragma unroll 4
  for (int j = 0; j < 96; j++)
    part = fmaf(s_h[wv][p*96 + j], b2f(Wd[(size_t)(p*96 + j)*16 + o]), part);
  part += __shfl_xor(part, 16);
  part += __shfl_xor(part, 32);
  const float y = geluf(part + b2f(bd[o]));
  float up[6] = {0.f,0.f,0.f,0.f,0.f,0.f};
  #pragma unroll
  for (int o2 = 0; o2 < 16; o2++){
    const float yo = __shfl(y, o2);
    #pragma unroll
    for (int i = 0; i < 6; i++)
      up[i] = fmaf(yo, b2f(Wu[(size_t)o2*384 + lane + 64*i]), up[i]);
  }
  const bool isf = (*flag != 0);
  #pragma unroll
  for (int i = 0; i < 6; i++){
    const int c = lane + 64*i;
    const float ov = v[i] + up[i] + b2f(bu[c]);
    if (isf) ((float*)out)[row*384 + c] = ov;
    else     ((bf16*)out)[row*384 + c] = f2b(ov);
  }
}

// ---------------------------------------------------------------------------
// Fused local branch v5b: direct Q/K frag global loads, reg-staged V with
// cross-chunk prefetch, __launch_bounds__(512, 2). Proven: 156us, no spill.
// ---------------------------------------------------------------------------
__global__ __launch_bounds__(512, 2) void local_kernel(
    const bf16* __restrict__ qkv3, const float* __restrict__ xres,
    const int* __restrict__ idx, const int* __restrict__ cidx,
    const bf16* __restrict__ Bp, const bf16* __restrict__ bp1,
    const bf16* __restrict__ bng, const bf16* __restrict__ bnb,
    const bf16* __restrict__ bnm, const bf16* __restrict__ bnv,
    const int* __restrict__ p_ifmm, const int* __restrict__ p_ccof,
    float* __restrict__ vis)
{
  __shared__ __align__(16) bf16 sV[3*4*64*8];  // V B-frags [h][nt][lane][8]
  __shared__ __align__(16) bf16 sP[3*2*64*8];  // P A-frags [h][mt][lane][8]
  __shared__ __align__(16) bf16 sO[3*4*64*8];  // O A-frags [h][mt*2+k0][lane][8]
  __shared__ int s_flat[32];
  __shared__ int s_tok[32];

  const int g = blockIdx.x;
  const int t = threadIdx.x, lane = t & 63, w = t >> 6;
  const int l15 = lane & 15, quad = lane >> 4;
  const int lanez = swzl(lane);                // swizzled frag-lane for LDS reads

  if (t < 32){
    const int r = idx[g*32 + t];
    s_flat[t] = r;
    s_tok[t]  = (r >> 9)*513 + 1 + (r & 511);
  }
  __syncthreads();

  // V staging geometry: 768 16B-chunks per chunk-iter; thread handles chA=t
  // (all) and chB=512+t (t<256 only).
  const int vrowA = t & 31,          vccA = t >> 5;            // 0..15
  const int vrowB = (512 + t) & 31,  vccB = (512 + t) >> 5;    // 16..23
  const int vhA = vccA >> 3, vd0A = (vccA & 7) * 8;
  const int vhB = vccB >> 3, vd0B = (vccB & 7) * 8;
  const bool hasB = (t < 256);

  uint4 svA, svB;
  {  // prefetch V(chunk 0)
    svA = *(const uint4*)(qkv3 + (size_t)s_flat[vrowA]*1152 + 768 + (0*3 + vhA)*64 + vd0A);
    if (hasB) svB = *(const uint4*)(qkv3 + (size_t)s_flat[vrowB]*1152 + 768 + (0*3 + vhB)*64 + vd0B);
  }

  f32x4 accp[3][2];
  #pragma unroll
  for (int a = 0; a < 3; a++){
    #pragma unroll
    for (int m = 0; m < 2; m++) accp[a][m] = f32x4{0.f,0.f,0.f,0.f};
  }

  #pragma unroll
  for (int hc = 0; hc < 2; hc++){
    // ---- write staged V regs -> sV (scatter-transpose, swizzled)
    {
      const bf16* sa = (const bf16*)&svA;
      #pragma unroll
      for (int j2 = 0; j2 < 8; j2++){
        const int d = vd0A + j2;
        const int L = (vrowA>>3)*16 + (d&15);
        sV[((vhA*4 + (d>>4))*64 + swzl(L))*8 + (vrowA&7)] = sa[j2];
      }
      if (hasB){
        const bf16* sb = (const bf16*)&svB;
        #pragma unroll
        for (int j2 = 0; j2 < 8; j2++){
          const int d = vd0B + j2;
          const int L = (vrowB>>3)*16 + (d&15);
          sV[((vhB*4 + (d>>4))*64 + swzl(L))*8 + (vrowB&7)] = sb[j2];
        }
      }
    }
    __syncthreads();

    // ---- phase 1: QK^T direct-from-global + softmax (waves 0..5) -> sP
    if (w < 6){
      const int h = w >> 1, mt = w & 1;
      const size_t qrow = (size_t)s_flat[mt*16 + l15]*1152;
      const int dcol = (hc*3 + h)*64 + quad*8;
      const short8 q0 = *(const short8*)(qkv3 + qrow + dcol);
      const short8 q1 = *(const short8*)(qkv3 + qrow + dcol + 32);
      f32x4 sr[2];
      #pragma unroll
      for (int nt = 0; nt < 2; nt++){
        const size_t krow = (size_t)s_flat[nt*16 + l15]*1152 + 384;
        const short8 k0 = *(const short8*)(qkv3 + krow + dcol);
        const short8 k1 = *(const short8*)(qkv3 + krow + dcol + 32);
        f32x4 acc = mfma16(q0, k0, f32x4{0.f,0.f,0.f,0.f});
        acc = mfma16(q1, k1, acc);
        #pragma unroll
        for (int r = 0; r < 4; r++) sr[nt][r] = acc[r]*0.125f;
      }
      #pragma unroll
      for (int r = 0; r < 4; r++){
        float mx = fmaxf(sr[0][r], sr[1][r]);
        #pragma unroll
        for (int mm = 8; mm; mm >>= 1) mx = fmaxf(mx, __shfl_xor(mx, mm));
        const float e0 = __expf(sr[0][r] - mx), e1 = __expf(sr[1][r] - mx);
        float sm = e0 + e1;
        #pragma unroll
        for (int mm = 8; mm; mm >>= 1) sm += __shfl_xor(sm, mm);
        const float inv = 1.f/sm;
        const int m = quad*4 + r;
        const int L0 = (l15 >> 3)*16       + m;
        const int L1 = (2 + (l15 >> 3))*16 + m;
        sP[((h*2 + mt)*64 + swzl(L0))*8 + (l15 & 7)] = f2b(e0*inv);
        sP[((h*2 + mt)*64 + swzl(L1))*8 + (l15 & 7)] = f2b(e1*inv);
      }
    }
    __syncthreads();

    // ---- phase 2: O = P V (8 waves x 3 heads) -> sO
    {
      const int mt = w & 1, nt = w >> 1;   // nt in 0..3
      const int k0w = nt >> 1, qdw = (nt & 1)*2 + (l15 >> 3), jw = l15 & 7;
      #pragma unroll
      for (int h = 0; h < 3; h++){
        const short8 a = *(const short8*)(sP + ((h*2 + mt)*64 + lanez)*8);
        const short8 b = *(const short8*)(sV + ((h*4 + nt)*64 + lanez)*8);
        const f32x4 o = mfma16(a, b, f32x4{0.f,0.f,0.f,0.f});
        #pragma unroll
        for (int r = 0; r < 4; r++){
          const int L = qdw*16 + quad*4 + r;
          sO[((h*4 + mt*2 + k0w)*64 + swzl(L))*8 + jw] = f2b(o[r]);
        }
      }
    }
    __syncthreads();

    // ---- prefetch next chunk's V (hides HBM latency under proj)
    if (hc == 0){
      svA = *(const uint4*)(qkv3 + (size_t)s_flat[vrowA]*1152 + 768 + (3 + vhA)*64 + vd0A);
      if (hasB) svB = *(const uint4*)(qkv3 + (size_t)s_flat[vrowB]*1152 + 768 + (3 + vhB)*64 + vd0B);
    }

    // ---- phase 3: proj partials accp += O_h @ Wp[hg*64:(hg+1)*64, :]
    #pragma unroll
    for (int h = 0; h < 3; h++){
      short8 afr[2][2];
      #pragma unroll
      for (int mt = 0; mt < 2; mt++){
        #pragma unroll
        for (int k0l = 0; k0l < 2; k0l++)
          afr[mt][k0l] = *(const short8*)(sO + ((h*4 + mt*2 + k0l)*64 + lanez)*8);
      }
      const int hg2 = (hc*3 + h)*2;
      #pragma unroll
      for (int tt = 0; tt < 3; tt++){
        const int nt = w*3 + tt;
        #pragma unroll
        for (int k0l = 0; k0l < 2; k0l++){
          const short8 b = *(const short8*)(Bp + ((size_t)(nt*12 + hg2 + k0l)*64 + lane)*8);
          accp[tt][0] = mfma16(afr[0][k0l], b, accp[tt][0]);
          accp[tt][1] = mfma16(afr[1][k0l], b, accp[tt][1]);
        }
      }
    }
    __syncthreads();   // protect sP/sO/sV before next chunk
  }

  // ---- epilogue: +bias +resid, pool, BN, gelu, +ccof*center
  const float fmm  = scal(p_ifmm);
  const float ccof = scal(p_ccof);
  const int cr = cidx[g];
  const int ctok = (cr >> 9)*513 + 1 + (cr & 511);
  #pragma unroll
  for (int tt = 0; tt < 3; tt++){
    const int n = (w*3 + tt)*16 + l15;
    const float bb = b2f(bp1[n]);
    float mx = -3e30f, sm = 0.f;
    #pragma unroll
    for (int mt = 0; mt < 2; mt++){
      #pragma unroll
      for (int r = 0; r < 4; r++){
        const int tok = mt*16 + quad*4 + r;
        const float v = accp[tt][mt][r] + bb + xres[(size_t)s_tok[tok]*384 + n];
        mx = fmaxf(mx, v); sm += v;
      }
    }
    mx = fmaxf(mx, __shfl_xor(mx, 16)); sm += __shfl_xor(sm, 16);
    mx = fmaxf(mx, __shfl_xor(mx, 32)); sm += __shfl_xor(sm, 32);
    if (quad == 0){
      const float lc = (fmm != 0.f) ? (mx + sm*(1.f/32.f)) : mx;
      const float nr = (lc - b2f(bnm[n])) * rsqrtf(b2f(bnv[n]) + 1e-5f) * b2f(bng[n]) + b2f(bnb[n]);
      vis[(size_t)g*384 + n] = geluf(nr) + ccof * xres[(size_t)ctok*384 + n];
    }
  }
}

// ---------------------------------------------------------------------------
// Inverse-distance interp FUSED with the final adapter for non-cls tokens:
// nv = xres + pro_cof * (w @ vis) computed fully in-block (each block holds
// complete 384-col rows for its 8 tokens), then out = nv + gelu(nv@Wd+bd)@Wu
// + bu written straight to d_out. xres is NOT written back (nothing reads
// it afterwards for non-cls tokens); saves 50MB of xres round-trip + a
// 16416-block dispatch.
// ---------------------------------------------------------------------------
__global__ __launch_bounds__(256) void interp_fused_kernel(
    const bf16* __restrict__ c1, const bf16* __restrict__ c2,
    const float* __restrict__ vis, const int* __restrict__ p_pcof,
    const float* __restrict__ xres,
    const bf16* __restrict__ Wd, const bf16* __restrict__ bd,
    const bf16* __restrict__ Wu, const bf16* __restrict__ bu,
    const int* __restrict__ flag, void* __restrict__ out)
{
  __shared__ float s_w[8][128];
  __shared__ float s_red[2];
  __shared__ float s_h[8][384];
  const int b = blockIdx.y;
  const int n0 = blockIdx.x * 8;
  const int t = threadIdx.x;
  for (int ni = 0; ni < 8; ni++){
    const int n = n0 + ni;
    float wv = 0.f;
    if (t < 128){
      float d2 = 0.f;
      #pragma unroll
      for (int k = 0; k < 3; k++){
        const float a = b2f(c1[((size_t)b*512 + n)*3 + k]);
        const float c = b2f(c2[((size_t)b*128 + t)*3 + k]);
        const float df = a - c; d2 += df*df;
      }
      wv = 1.f/(d2 + 1e-8f);
    }
    float rsum = wv;
    #pragma unroll
    for (int mm = 32; mm; mm >>= 1) rsum += __shfl_xor(rsum, mm);
    if (((t & 63) == 0) && t < 128) s_red[t >> 6] = rsum;
    __syncthreads();
    const float tot = s_red[0] + s_red[1];
    if (t < 128) s_w[ni][t] = wv / tot;
    __syncthreads();
  }
  float acc1[8], acc2[8];
  #pragma unroll
  for (int ni = 0; ni < 8; ni++){ acc1[ni] = 0.f; acc2[ni] = 0.f; }
  for (int s = 0; s < 128; s++){
    const float* vp = vis + ((size_t)b*128 + s)*384;
    const float v1 = vp[t];
    const float v2 = (t < 128) ? vp[t + 256] : 0.f;
    #pragma unroll
    for (int ni = 0; ni < 8; ni++){
      const float wn = s_w[ni][s];
      acc1[ni] = fmaf(wn, v1, acc1[ni]);
      acc2[ni] = fmaf(wn, v2, acc2[ni]);
    }
  }
  const float pc = scal(p_pcof);
  #pragma unroll
  for (int ni = 0; ni < 8; ni++){
    const int tok = b*513 + 1 + n0 + ni;
    s_h[ni][t] = xres[(size_t)tok*384 + t] + pc*acc1[ni];
    if (t < 128) s_h[ni][t + 256] = xres[(size_t)tok*384 + t + 256] + pc*acc2[ni];
  }
  __syncthreads();

  // ---- fused final adapter: 4 waves x 2 passes over the 8 rows
  const int wv4 = t >> 6, lane = t & 63;
  const int o = lane & 15, p = lane >> 4;
  const bool isf = (*flag != 0);
  #pragma unroll
  for (int pass = 0; pass < 2; pass++){
    const int r8 = wv4 + pass*4;           // row 0..7
    const int tok = b*513 + 1 + n0 + r8;
    float part = 0.f;
    #pragma unroll 4
    for (int j = 0; j < 96; j++)
      part = fmaf(s_h[r8][p*96 + j], b2f(Wd[(size_t)(p*96 + j)*16 + o]), part);
    part += __shfl_xor(part, 16);
    part += __shfl_xor(part, 32);
    const float y = geluf(part + b2f(bd[o]));
    #pragma unroll
    for (int i = 0; i < 6; i++){
      const int c = lane + 64*i;
      float up = 0.f;
      #pragma unroll
      for (int o2 = 0; o2 < 16; o2++)
        up = fmaf(__shfl(y, o2), b2f(Wu[(size_t)o2*384 + c]), up);
      const float ov = s_h[r8][c] + up + b2f(bu[c]);
      if (isf) ((float*)out)[(size_t)tok*384 + c] = ov;
      else     ((bf16*)out)[(size_t)tok*384 + c] = f2b(ov);
    }
  }
}

// ---------------------------------------------------------------------------
extern "C" void kernel_launch(void* const* d_in, const int* in_sizes, int n_in,
                              void* d_out, int out_size, void* d_ws, size_t ws_size,
                              hipStream_t stream)
{
  (void)n_in; (void)out_size; (void)ws_size;
  const int*  idx   = (const int*)d_in[35];
  const int*  cidx  = (const int*)d_in[36];
  const int*  ifmm  = (const int*)d_in[38];
  const int*  pcof  = (const int*)d_in[39];
  const int*  ccof  = (const int*)d_in[40];

  size_t off = 0;
  auto alloc = [&](size_t bytes) -> void* {
    void* p = (char*)d_ws + off; off += (bytes + 255) & ~(size_t)255; return p;
  };
  int*   flag = (int*)  alloc(sizeof(int));
  float* xres = (float*)alloc((size_t)TOK*384*4);
  bf16*  slab = (bf16*) alloc((size_t)TOK*1536*2);
  bf16*  xn   = (bf16*) alloc((size_t)TOK*384*2);
  float* pq   = (float*)alloc((size_t)10*1152*4);
  bf16*  Bq   = (bf16*) alloc((size_t)72*12*64*8*2);   // shuffled a1_Wqkv
  bf16*  Bp   = (bf16*) alloc((size_t)24*12*64*8*2);   // shuffled a1_Wproj
  bf16*  Bqkv = (bf16*) alloc((size_t)72*12*64*8*2);   // shuffled Wqkv
  bf16*  Bw1  = (bf16*) alloc((size_t)96*12*64*8*2);   // shuffled W1
  bf16*  Bw2  = (bf16*) alloc((size_t)24*48*64*8*2);   // shuffled W2
  bf16*  Bwp  = (bf16*) alloc((size_t)24*12*64*8*2);   // shuffled Wproj

  // slab overlays (time-phased):
  //   A: qkvb [0, TOK*1152) + canonical-x [TOK*1152, TOK*1536)
  //   B: h1   [0, TOK*1536)
  //   C: qkv3 [0, 16384*1152) + xln3 [TOK*1152, +16384*384)
  bf16*  qkvb = slab;
  bf16*  x_c  = slab + (size_t)TOK*1152;
  bf16*  h1   = slab;
  bf16*  qkv3 = slab;
  bf16*  xln3 = slab + (size_t)TOK*1152;
  bf16*  ao   = xn;
  bf16*  hbuf = xn;
  float* visb = (float*)xn;   // vis (6.3 MB) overlays xn after h is consumed

  const int conv_ids[34] = {0,1,2,4,5,6,7,8,9,10,11,12,13,14,15,16,17,
                            18,19,20,21,22,23,24,25,26,27,28,29,30,31,32,33,34};
  ConvArgs ca;
  bf16* canon[41];
  int maxn = 1;
  for (int k = 0; k < 34; k++){
    const int i = conv_ids[k];
    const int n = in_sizes[i];
    bf16* dst = (i == 0) ? x_c : (bf16*)alloc((size_t)n*2);
    ca.src[k] = d_in[i]; ca.dst[k] = dst; ca.n[k] = n;
    canon[i] = dst;
    if (n > maxn) maxn = n;
  }
  detect_kernel<<<dim3(1), dim3(256), 0, stream>>>((const unsigned*)d_in[0], flag);
  {
    int gx = (maxn/8 + 255) / 256; if (gx > 512) gx = 512; if (gx < 1) gx = 1;
    convert_many<<<dim3(gx, 34), dim3(256), 0, stream>>>(flag, ca);
  }

  const bf16 *x_in = canon[0], *c1 = canon[1], *c2 = canon[2], *pe = canon[4],
             *ln1g = canon[5], *ln1b = canon[6], *Wqkv = canon[7], *Wproj = canon[8],
             *bproj = canon[9], *gate = canon[10], *ln2g = canon[11], *ln2b = canon[12],
             *W1 = canon[13], *b1 = canon[14], *W2 = canon[15], *b2v = canon[16],
             *adW = canon[17], *adb = canon[18], *adU = canon[19], *adub = canon[20],
             *adg = canon[21], *bng = canon[22], *bnb = canon[23], *bnm = canon[24],
             *bnv = canon[25], *ln3g = canon[26], *ln3b = canon[27], *a1W = canon[28],
             *a1P = canon[29], *a1pb = canon[30], *d1W = canon[31], *d1b = canon[32],
             *u1W = canon[33], *u1b = canon[34];

  // weight shuffles: all 6 in ONE dispatch (blockIdx.y selects weight)
  {
    ShufArgs sa;
    sa.W[0]=a1W;   sa.out[0]=Bq;   sa.N[0]=1152; sa.KT[0]=12; sa.NT[0]=72;
    sa.W[1]=a1P;   sa.out[1]=Bp;   sa.N[1]=384;  sa.KT[1]=12; sa.NT[1]=24;
    sa.W[2]=Wqkv;  sa.out[2]=Bqkv; sa.N[2]=1152; sa.KT[2]=12; sa.NT[2]=72;
    sa.W[3]=W1;    sa.out[3]=Bw1;  sa.N[3]=1536; sa.KT[3]=12; sa.NT[3]=96;
    sa.W[4]=W2;    sa.out[4]=Bw2;  sa.N[4]=384;  sa.KT[4]=48; sa.NT[4]=24;
    sa.W[5]=Wproj; sa.out[5]=Bwp;  sa.N[5]=384;  sa.KT[5]=12; sa.NT[5]=24;
    shuffle_many<<<dim3(288, 6), dim3(256), 0, stream>>>(sa);
  }

  // 1. LN1
  ln_kernel<true><<<dim3((TOK*64)/256), dim3(256), 0, stream>>>((const void*)x_in, ln1g, ln1b, xn, TOK);
  // 2. qkv = xn @ Wqkv (MFMA 128x128, async A-staging)
  mfma_gemm<1><<<dim3(9,129), dim3(256), 0, stream>>>(xn, Bqkv, nullptr, nullptr, qkvb, TOK, 1152, 384);
  // 2b. prompt qkv
  pqkv_kernel<<<dim3(18), dim3(256), 0, stream>>>(pe, Wqkv, pq);
  // 3. attention v4b (async dbuf K, reg-prefetched V, Q in regs) -> ao
  attn_kernel<<<dim3(9,192), dim3(256), 0, stream>>>(qkvb, pq, gate, ao);
  // 4. xres = x + ao @ Wproj + bproj
  mfma_gemm<3><<<dim3(3,129), dim3(256), 0, stream>>>(ao, Bwp, bproj, x_in, xres, TOK, 384, 384);
  // 5. LN2
  ln_kernel<false><<<dim3((TOK*64)/256), dim3(256), 0, stream>>>((const void*)xres, ln2g, ln2b, xn, TOK);
  // 6. h1 = gelu(xn @ W1 + b1)
  mfma_gemm<2><<<dim3(12,129), dim3(256), 0, stream>>>(xn, Bw1, b1, nullptr, h1, TOK, 1536, 384);
  // 7. h = h1 @ W2 + b2
  mfma_gemm<0><<<dim3(3,129), dim3(256), 0, stream>>>(h1, Bw2, b2v, nullptr, hbuf, TOK, 384, 1536);
  // 8. adapter mid (wave-per-row, fused LN3 -> xln3)
  adapter_mid_kernel<<<dim3(TOK/4), dim3(256), 0, stream>>>(
      hbuf, adW, adb, adU, adub, adg, ln3g, ln3b, xres, xln3);
  // 8c. qkv3 = xln3 @ a1_Wqkv (deduped, flat MFMA GEMM)
  mfma_gemm<1><<<dim3(9,128), dim3(256), 0, stream>>>(xln3, Bq, nullptr, nullptr, qkv3, 16384, 1152, 384);
  // 9. local branch v5b (direct Q/K frag loads, reg-staged V) -> vis
  local_kernel<<<dim3(4096), dim3(512), 0, stream>>>(qkv3, xres, idx, cidx, Bp, a1pb,
                                                     bng, bnb, bnm, bnv, ifmm, ccof, visb);
  // 10. interp FUSED with final adapter (non-cls tokens) -> d_out
  interp_fused_kernel<<<dim3(64,32), dim3(256), 0, stream>>>(
      c1, c2, visb, pcof, xres, d1W, d1b, u1W, u1b, flag, d_out);
  // 11. final adapter for the 32 cls tokens -> d_out
  cls_adapter_kernel<<<dim3(8), dim3(256), 0, stream>>>(
      xres, d1W, d1b, u1W, u1b, flag, d_out);
}

// Round 14
// 782.652 us; speedup vs baseline: 1.1107x; 1.1107x over previous
//
#include <hip/hip_runtime.h>
#include <hip/hip_bf16.h>
#include <cstdint>
#include <cstddef>

// Problem constants: B=32, G=512, S=128, GS=32, P=10, C=384, H=6, D=64,
// HID=1536, RED=16, tokens per batch = 513.
typedef __hip_bfloat16 bf16;
constexpr int TOK = 32 * 513;   // 16416 rows in the residual stream

typedef __attribute__((ext_vector_type(8))) short short8;
typedef __attribute__((ext_vector_type(4))) float f32x4;

__device__ __forceinline__ float bflo(unsigned u){ return __uint_as_float(u << 16); }
__device__ __forceinline__ float bfhi(unsigned u){ return __uint_as_float(u & 0xffff0000u); }
__device__ __forceinline__ float b2f(bf16 x){ return __bfloat162float(x); }
__device__ __forceinline__ bf16  f2b(float x){ return __float2bfloat16(x); }
__device__ __forceinline__ float geluf(float x){ return 0.5f*x*(1.0f + erff(x*0.70710678118654752f)); }
// Scalar decode robust to int32-vs-float32 materialization of Python scalars.
__device__ __forceinline__ float scal(const int* p){
  const int i = *p;
  if (i > -1000000 && i < 1000000) return (float)i;
  return __int_as_float(i);
}
__device__ __forceinline__ f32x4 mfma16(short8 a, short8 b, f32x4 c){
  return __builtin_amdgcn_mfma_f32_16x16x32_bf16(a, b, c, 0, 0, 0);
}
// XOR swizzle of a frag-lane index (16B LDS slot within a 64-slot tile):
// spreads bank groups using bits 3-5 so scatter writes don't serialize.
__device__ __forceinline__ int swzl(int l){ return l ^ ((l >> 3) & 7); }
// Async global->LDS 16B per lane (wave-uniform LDS base + lane*16).
__device__ __forceinline__ void gload_lds16(const bf16* g, bf16* l){
  __builtin_amdgcn_global_load_lds(
      (const __attribute__((address_space(1))) void*)g,
      (__attribute__((address_space(3))) void*)l, 16, 0, 0);
}

// ---------------------------------------------------------------------------
// Dtype detection: fp32 vs bf16 inputs.
// ---------------------------------------------------------------------------
__global__ __launch_bounds__(256) void detect_kernel(const unsigned* __restrict__ x,
                                                     int* __restrict__ flag)
{
  const int t = threadIdx.x;
  bool bad = false;
  for (int i = t; i < 2048; i += 256){
    const unsigned u = x[i];
    const float a = fabsf(bflo(u)), b = fabsf(bfhi(u));
    if (!(a < 1e6f) || !(b < 1e6f)) bad = true;
  }
  __shared__ int s;
  if (t == 0) s = 0;
  __syncthreads();
  const unsigned long long m = __ballot(bad);
  if (m != 0ull && (t & 63) == 0) atomicOr(&s, 1);
  __syncthreads();
  if (t == 0) *flag = s;
}

// ---------------------------------------------------------------------------
// Canonicalize all float inputs to bf16 (copy if already bf16).
// v2: 8 elements/thread (2x float4 load -> 16B bf16 store), scalar tail.
// ---------------------------------------------------------------------------
struct ConvArgs {
  const void* src[34];
  bf16*       dst[34];
  int         n[34];
};
__global__ __launch_bounds__(256) void convert_many(const int* __restrict__ flag, ConvArgs a)
{
  const int ii = blockIdx.y;
  const bool isf = (*flag != 0);
  const int n = a.n[ii];
  const int n8 = n >> 3;
  bf16* d = a.dst[ii];
  if (isf){
    const float4* s = (const float4*)a.src[ii];
    for (int i = blockIdx.x*256 + threadIdx.x; i < n8; i += gridDim.x*256){
      const float4 f0 = s[i*2];
      const float4 f1 = s[i*2 + 1];
      bf16 tmp[8] = {f2b(f0.x),f2b(f0.y),f2b(f0.z),f2b(f0.w),
                     f2b(f1.x),f2b(f1.y),f2b(f1.z),f2b(f1.w)};
      *(uint4*)(d + (size_t)i*8) = *(const uint4*)tmp;
    }
  } else {
    const uint4* s = (const uint4*)a.src[ii];
    for (int i = blockIdx.x*256 + threadIdx.x; i < n8; i += gridDim.x*256){
      ((uint4*)d)[i] = s[i];
    }
  }
  if (blockIdx.x == 0){
    for (int i = n8*8 + threadIdx.x; i < n; i += 256){
      d[i] = isf ? f2b(((const float*)a.src[ii])[i]) : ((const bf16*)a.src[ii])[i];
    }
  }
}

// ---------------------------------------------------------------------------
// Shuffle 6 weights W[K x N] (row-major) into MFMA B-fragment order in ONE
// dispatch (blockIdx.y = which weight; 5 launch gaps deleted).
// ---------------------------------------------------------------------------
struct ShufArgs {
  const bf16* W[6];
  bf16*       out[6];
  int         N[6];
  int         KT[6];
  int         NT[6];
};
__global__ __launch_bounds__(256) void shuffle_many(ShufArgs a)
{
  const int ii = blockIdx.y;
  const int id = blockIdx.x*256 + threadIdx.x;
  const int KT = a.KT[ii], NT = a.NT[ii], N = a.N[ii];
  if (id >= NT*KT*64) return;
  const int l  = id & 63;
  const int k0 = (id >> 6) % KT;
  const int n0 = (id >> 6) / KT;
  const bf16* W = a.W[ii];
  bf16 tmp[8];
  #pragma unroll
  for (int j = 0; j < 8; j++)
    tmp[j] = W[(size_t)(k0*32 + (l>>4)*8 + j)*N + n0*16 + (l&15)];
  *(uint4*)(a.out[ii] + (size_t)id*8) = *(const uint4*)tmp;
}

// ---------------------------------------------------------------------------
// LayerNorm: one wave per row of 384. Output bf16.
// ---------------------------------------------------------------------------
template<bool SRC_BF16>
__global__ __launch_bounds__(256) void ln_kernel(const void* __restrict__ src,
    const bf16* __restrict__ g, const bf16* __restrict__ b,
    bf16* __restrict__ out, int rows)
{
  const int wave = (blockIdx.x * blockDim.x + threadIdx.x) >> 6;
  const int lane = threadIdx.x & 63;
  if (wave >= rows) return;
  float v[6]; float s = 0.f, s2 = 0.f;
  #pragma unroll
  for (int i = 0; i < 6; i++){
    const int c = lane + 64*i;
    float x;
    if (SRC_BF16) x = b2f(((const bf16*)src)[(size_t)wave*384 + c]);
    else          x = ((const float*)src)[(size_t)wave*384 + c];
    v[i] = x; s += x; s2 += x*x;
  }
  #pragma unroll
  for (int mm = 32; mm; mm >>= 1){ s += __shfl_xor(s, mm); s2 += __shfl_xor(s2, mm); }
  const float mean = s * (1.f/384.f);
  const float rs = rsqrtf(s2 * (1.f/384.f) - mean*mean + 1e-5f);
  #pragma unroll
  for (int i = 0; i < 6; i++){
    const int c = lane + 64*i;
    out[(size_t)wave*384 + c] = f2b((v[i]-mean)*rs*b2f(g[c]) + b2f(b[c]));
  }
}

// ---------------------------------------------------------------------------
// MFMA GEMM v2: out[M,N] = A[M,K] @ W[K,N] (+bias, epilogue). A bf16 row-major,
// Bsh = W pre-shuffled to B-frag order. Block 128x128, BK=32, 256 thr (2x2
// wave grid, 4x4 16x16 tiles per wave). A staged via ASYNC global_load_lds
// width-16. EPI: 0 = bf16 out, +bias; 1 = bf16 out; 2 = bf16 gelu(+bias);
//      3 = f32 out, +bias +bf16resid
// ---------------------------------------------------------------------------
template<int EPI>
__global__ __launch_bounds__(256) void mfma_gemm(
    const bf16* __restrict__ A, const bf16* __restrict__ Bsh,
    const bf16* __restrict__ bias, const bf16* __restrict__ resid,
    void* __restrict__ outv, int M, int N, int K)
{
  __shared__ __align__(16) bf16 sA[8*64*8];   // 128x32 A tile in frag order
  const int t = threadIdx.x, lane = t & 63, w = t >> 6;
  const int l15 = lane & 15, quad = lane >> 4;
  const int wm = w & 1, wn = w >> 1;          // 2x2 wave grid
  const int m0 = blockIdx.y * 128;
  const int n0t = blockIdx.x * 8 + wn * 4;    // this wave's global n-tile base
  const int KT = K >> 5;
  f32x4 acc[4][4];
  #pragma unroll
  for (int i = 0; i < 4; i++){
    #pragma unroll
    for (int j = 0; j < 4; j++) acc[i][j] = f32x4{0.f,0.f,0.f,0.f};
  }
  // staging geometry: wave w owns m-tiles 2w and 2w+1
  const int mtA = 2*w, mtB = 2*w + 1;
  const bf16* gA = A + (size_t)(m0 + mtA*16 + l15)*K + quad*8;
  const bf16* gB = A + (size_t)(m0 + mtB*16 + l15)*K + quad*8;
  bf16* lA = sA + mtA*512;   // 64 lanes x 8 bf16 per tile
  bf16* lB = sA + mtB*512;

  for (int ks = 0; ks < KT; ks++){
    gload_lds16(gA + ks*32, lA);
    gload_lds16(gB + ks*32, lB);
    __syncthreads();   // drains vmcnt -> staged data visible
    short8 afr[4];
    #pragma unroll
    for (int i = 0; i < 4; i++)
      afr[i] = *(const short8*)(sA + (((wm*4+i)*64 + lane) << 3));
    #pragma unroll
    for (int j = 0; j < 4; j++){
      const short8 b = *(const short8*)(Bsh + ((size_t)((n0t+j)*KT + ks)*64 + lane)*8);
      #pragma unroll
      for (int i = 0; i < 4; i++) acc[i][j] = mfma16(afr[i], b, acc[i][j]);
    }
    __syncthreads();
  }
  #pragma unroll
  for (int i = 0; i < 4; i++){
    #pragma unroll
    for (int r = 0; r < 4; r++){
      const int gm = m0 + (wm*4+i)*16 + quad*4 + r;
      if (gm < M){
        #pragma unroll
        for (int j = 0; j < 4; j++){
          const int gn = (n0t+j)*16 + l15;
          float v = acc[i][j][r];
          const size_t o = (size_t)gm*N + gn;
          if (EPI == 0){ v += b2f(bias[gn]); ((bf16*)outv)[o] = f2b(v); }
          else if (EPI == 1){ ((bf16*)outv)[o] = f2b(v); }
          else if (EPI == 2){ v += b2f(bias[gn]); ((bf16*)outv)[o] = f2b(geluf(v)); }
          else { v += b2f(bias[gn]) + b2f(resid[o]); ((float*)outv)[o] = v; }
        }
      }
    }
  }
}

// ---------------------------------------------------------------------------
// Prompt QKV: (10 x 384) @ (384 x 1152) -> f32 (prompt used WITHOUT LN).
// ---------------------------------------------------------------------------
__global__ __launch_bounds__(256) void pqkv_kernel(const bf16* __restrict__ pe,
    const bf16* __restrict__ Wqkv, float* __restrict__ pq)
{
  const int n  = blockIdx.x*64 + (threadIdx.x & 63);
  const int rg = threadIdx.x >> 6;
  for (int r = rg; r < 10; r += 4){
    float s0 = 0.f, s1 = 0.f;
    for (int c = 0; c < 384; c += 2){
      s0 = fmaf(b2f(pe[(size_t)r*384+c]),   b2f(Wqkv[(size_t)c*1152 + n]),     s0);
      s1 = fmaf(b2f(pe[(size_t)r*384+c+1]), b2f(Wqkv[(size_t)(c+1)*1152 + n]), s1);
    }
    pq[(size_t)r*1152 + n] = s0 + s1;
  }
}

// ---------------------------------------------------------------------------
// Main attention v4b (MFMA flash) + prompt cross-attention fused.
// Q frags in registers; K async double-buffered via gload_lds16; V
// reg-prefetched (issue-early/write-late); s_p stride 64 (collision-free).
// ---------------------------------------------------------------------------
__global__ __launch_bounds__(256) void attn_kernel(
    const bf16* __restrict__ qkv, const float* __restrict__ pq,
    const bf16* __restrict__ gate, bf16* __restrict__ ao)
{
  __shared__ __align__(16) bf16 s_kf[2][8*64*8];  // K frags [buf][nt*2+half][lane][8]
  __shared__ __align__(16) bf16 s_vT[64*72];
  __shared__ __align__(16) bf16 s_p[4*16*64];     // P [wave][row][col], stride 64
  __shared__ __align__(16) bf16 s_pk[16*72];
  __shared__ __align__(16) bf16 s_pvT[64*40];
  const int bh = blockIdx.y;
  const int b = bh / 6, h = bh % 6;
  const int q0 = blockIdx.x * 64;
  const int t = threadIdx.x, lane = t & 63, w = t >> 6;
  const int l15 = lane & 15, quad = lane >> 4;

  // Q frags: direct global, loop-invariant (A-frag: row l15, cols quad*8..+7)
  const int qtok = q0 + w*16 + l15;
  const int qtokc = qtok < 513 ? qtok : 512;
  const bf16* qp = qkv + (size_t)(b*513 + qtokc)*1152 + h*64 + quad*8;
  const short8 qf0 = *(const short8*)qp;
  const short8 qf1 = *(const short8*)(qp + 32);

  // per-lane K staging source (row l15 of this wave's tile, clamped)
  auto issueK = [&](int kb, int buf){
    const int key = kb + w*16 + l15;
    const int keyc = key < 513 ? key : 512;
    const bf16* src = qkv + (size_t)(b*513 + keyc)*1152 + 384 + h*64 + quad*8;
    gload_lds16(src,      &s_kf[buf][((w*2 + 0)*64)*8]);
    gload_lds16(src + 32, &s_kf[buf][((w*2 + 1)*64)*8]);
  };

  // V prefetch geometry (2 keys per thread)
  const int kp = t & 31, dg = t >> 5;

  {
    const int j = t >> 4, dc = (t & 15) * 4;
    float f[4] = {0.f,0.f,0.f,0.f};
    if (j < 10){
      const float* pk = pq + (size_t)j*1152 + 384 + h*64 + dc;
      f[0]=pk[0]; f[1]=pk[1]; f[2]=pk[2]; f[3]=pk[3];
    }
    bf16 tmp[4] = {f2b(f[0]),f2b(f[1]),f2b(f[2]),f2b(f[3])};
    *(uint2*)(s_pk + j*72 + dc) = *(const uint2*)tmp;
  }
  {
    const int d = t & 63, kg = t >> 6;
    #pragma unroll
    for (int kk = 0; kk < 8; kk++){
      const int key = kg*8 + kk;
      bf16 v = f2b(0.f);
      if (key < 10) v = f2b(pq[(size_t)key*1152 + 768 + h*64 + d]);
      s_pvT[d*40 + key] = v;
    }
  }

  // prologue: prefetch V(0), issue async K(0) -> buf 0
  uint4 pv0 = {0,0,0,0}, pv1 = {0,0,0,0};
  {
    const int key0 = 2*kp;
    if (key0 < 513)
      pv0 = *(const uint4*)(qkv + (size_t)(b*513 + key0)*1152 + 768 + h*64 + dg*8);
    if (key0 + 1 < 513)
      pv1 = *(const uint4*)(qkv + (size_t)(b*513 + key0 + 1)*1152 + 768 + h*64 + dg*8);
  }
  issueK(0, 0);
  int cur = 0;

  float m_i[4], l_i[4];
  f32x4 oacc[4];
  #pragma unroll
  for (int r = 0; r < 4; r++){ m_i[r] = -30000.f; l_i[r] = 0.f; }
  #pragma unroll
  for (int nt = 0; nt < 4; nt++) oacc[nt] = f32x4{0.f,0.f,0.f,0.f};
  bf16* myp = s_p + w*16*64;

  for (int kt = 0; kt < 9; kt++){
    const int kb = kt*64;
    __syncthreads();   // drains async K(kt) into s_kf[cur]; prev PV done -> s_vT writable
    {   // write prefetched V(kt) regs -> s_vT (transpose)
      const unsigned short* a0 = (const unsigned short*)&pv0;
      const unsigned short* a1 = (const unsigned short*)&pv1;
      unsigned* vt = (unsigned*)s_vT;
      #pragma unroll
      for (int j = 0; j < 8; j++)
        vt[(dg*8 + j)*36 + kp] = (unsigned)a0[j] | ((unsigned)a1[j] << 16);
    }
    __syncthreads();   // s_vT ready

    f32x4 sreg[4];
    #pragma unroll
    for (int nt = 0; nt < 4; nt++){
      const short8 kf0 = *(const short8*)(&s_kf[cur][((nt*2 + 0)*64 + lane)*8]);
      const short8 kf1 = *(const short8*)(&s_kf[cur][((nt*2 + 1)*64 + lane)*8]);
      f32x4 acc = mfma16(qf0, kf0, f32x4{0.f,0.f,0.f,0.f});
      acc = mfma16(qf1, kf1, acc);
      const bool kvalid = (kb + nt*16 + l15) < 513;
      #pragma unroll
      for (int r = 0; r < 4; r++)
        sreg[nt][r] = kvalid ? acc[r]*0.125f : -30000.f;
    }

    // prefetch for kt+1: async K (cold buffer) + V regs; both drain/land at
    // the next top-of-loop barrier, hidden under softmax+PV below.
    if (kt < 8){
      issueK(kb + 64, cur ^ 1);
      const int key0 = kb + 64 + 2*kp;
      pv0 = {0,0,0,0}; pv1 = {0,0,0,0};
      if (key0 < 513)
        pv0 = *(const uint4*)(qkv + (size_t)(b*513 + key0)*1152 + 768 + h*64 + dg*8);
      if (key0 + 1 < 513)
        pv1 = *(const uint4*)(qkv + (size_t)(b*513 + key0 + 1)*1152 + 768 + h*64 + dg*8);
    }

    float alpha[4];
    #pragma unroll
    for (int r = 0; r < 4; r++){
      float mx = fmaxf(fmaxf(sreg[0][r], sreg[1][r]), fmaxf(sreg[2][r], sreg[3][r]));
      #pragma unroll
      for (int mm = 8; mm; mm >>= 1) mx = fmaxf(mx, __shfl_xor(mx, mm));
      const float mn = fmaxf(m_i[r], mx);
      alpha[r] = __expf(m_i[r] - mn);
      m_i[r] = mn;
      float ps = 0.f;
      #pragma unroll
      for (int nt = 0; nt < 4; nt++){
        const float p = __expf(sreg[nt][r] - mn);
        sreg[nt][r] = p; ps += p;
      }
      #pragma unroll
      for (int mm = 8; mm; mm >>= 1) ps += __shfl_xor(ps, mm);
      l_i[r] = l_i[r]*alpha[r] + ps;
    }
    #pragma unroll
    for (int nt = 0; nt < 4; nt++){
      #pragma unroll
      for (int r = 0; r < 4; r++)
        myp[(quad*4 + r)*64 + nt*16 + l15] = f2b(sreg[nt][r]);
    }
    #pragma unroll
    for (int nt = 0; nt < 4; nt++){
      #pragma unroll
      for (int r = 0; r < 4; r++) oacc[nt][r] *= alpha[r];
    }
    const short8* ap = (const short8*)(myp + l15*64);
    #pragma unroll
    for (int nt = 0; nt < 4; nt++){
      const short8* bv = (const short8*)(s_vT + (nt*16 + l15)*72);
      oacc[nt] = mfma16(ap[quad],     bv[quad],     oacc[nt]);
      oacc[nt] = mfma16(ap[4 + quad], bv[4 + quad], oacc[nt]);
    }
    cur ^= 1;
  }

  f32x4 sp;
  {
    f32x4 acc = f32x4{0.f,0.f,0.f,0.f};
    const short8* bp = (const short8*)(s_pk + l15*72);
    acc = mfma16(qf0, bp[quad],     acc);
    acc = mfma16(qf1, bp[4 + quad], acc);
    #pragma unroll
    for (int r = 0; r < 4; r++)
      sp[r] = (l15 < 10) ? acc[r]*0.125f : -30000.f;
  }
  float psr[4];
  #pragma unroll
  for (int r = 0; r < 4; r++){
    float mx = sp[r];
    #pragma unroll
    for (int mm = 8; mm; mm >>= 1) mx = fmaxf(mx, __shfl_xor(mx, mm));
    const float p = __expf(sp[r] - mx);
    float ps = p;
    #pragma unroll
    for (int mm = 8; mm; mm >>= 1) ps += __shfl_xor(ps, mm);
    psr[r] = ps;
    myp[(quad*4 + r)*64 + l15]      = f2b(p);
    myp[(quad*4 + r)*64 + 16 + l15] = f2b(0.f);
  }
  f32x4 pva[4];
  {
    const short8* ap = (const short8*)(myp + l15*64);
    #pragma unroll
    for (int nt = 0; nt < 4; nt++){
      const short8* bv = (const short8*)(s_pvT + (nt*16 + l15)*40);
      pva[nt] = mfma16(ap[quad], bv[quad], f32x4{0.f,0.f,0.f,0.f});
    }
  }

  const float gh = b2f(gate[h]);
  #pragma unroll
  for (int r = 0; r < 4; r++){
    const int tok = q0 + w*16 + quad*4 + r;
    if (tok < 513){
      const float invl = 1.f/l_i[r];
      const float gps  = gh/psr[r];
      #pragma unroll
      for (int nt = 0; nt < 4; nt++){
        const float val = oacc[nt][r]*invl + pva[nt][r]*gps;
        ao[(size_t)(b*513 + tok)*384 + h*64 + nt*16 + l15] = f2b(val);
      }
    }
  }
}

// ---------------------------------------------------------------------------
// Adapter v2: one WAVE per row (4 waves / 256-thr block, no barriers).
// y = gelu(h@Wd+bd) via lane(o=l&15,p=l>>4) partial + shfl_xor reduce;
// up = y@Wu via 16 shfl broadcasts. MID: xres = g*(h+up+bu) + xres, and
// FUSED LN3 (writes xln3 for non-cls tokens). !MID: out = h+up+bu (dtype flag).
// ---------------------------------------------------------------------------
template<bool MID>
__global__ __launch_bounds__(256) void adapter_kernel(
    const void* __restrict__ src,
    const bf16* __restrict__ Wd, const bf16* __restrict__ bd,
    const bf16* __restrict__ Wu, const bf16* __restrict__ bu,
    const bf16* __restrict__ p_gate,
    const bf16* __restrict__ g3, const bf16* __restrict__ b3,
    const int* __restrict__ flag,
    float* __restrict__ xres, bf16* __restrict__ xln3,
    void* __restrict__ out)
{
  __shared__ float s_h[4][384];
  const int wv = threadIdx.x >> 6, lane = threadIdx.x & 63;
  const int row = blockIdx.x*4 + wv;        // grid = TOK/4 exactly
  float v[6];
  #pragma unroll
  for (int i = 0; i < 6; i++){
    const int c = lane + 64*i;
    float x;
    if (MID) x = b2f(((const bf16*)src)[(size_t)row*384 + c]);
    else     x = ((const float*)src)[(size_t)row*384 + c];
    v[i] = x; s_h[wv][c] = x;
  }
  // same-wave LDS write->read is ordered; no barrier needed (per-wave slice)
  const int o = lane & 15, p = lane >> 4;
  float part = 0.f;
  #pragma unroll 4
  for (int j = 0; j < 96; j++)
    part = fmaf(s_h[wv][p*96 + j], b2f(Wd[(size_t)(p*96 + j)*16 + o]), part);
  part += __shfl_xor(part, 16);
  part += __shfl_xor(part, 32);
  const float y = geluf(part + b2f(bd[o]));   // lanes with equal o agree
  float up[6] = {0.f,0.f,0.f,0.f,0.f,0.f};
  #pragma unroll
  for (int o2 = 0; o2 < 16; o2++){
    const float yo = __shfl(y, o2);
    #pragma unroll
    for (int i = 0; i < 6; i++)
      up[i] = fmaf(yo, b2f(Wu[(size_t)o2*384 + lane + 64*i]), up[i]);
  }
  if (MID){
    const float g = b2f(p_gate[0]);
    float nv[6]; float s = 0.f, s2 = 0.f;
    #pragma unroll
    for (int i = 0; i < 6; i++){
      const int c = lane + 64*i;
      const float had = v[i] + up[i] + b2f(bu[c]);
      const float nx = g*had + xres[(size_t)row*384 + c];
      xres[(size_t)row*384 + c] = nx;
      nv[i] = nx; s += nx; s2 += nx*nx;
    }
    const int boff = row % 513;
    if (boff != 0){   // fused LN3 for non-cls tokens
      #pragma unroll
      for (int mm = 32; mm; mm >>= 1){ s += __shfl_xor(s, mm); s2 += __shfl_xor(s2, mm); }
      const float mean = s * (1.f/384.f);
      const float rs = rsqrtf(s2 * (1.f/384.f) - mean*mean + 1e-5f);
      const int r3 = (row/513)*512 + boff - 1;
      #pragma unroll
      for (int i = 0; i < 6; i++){
        const int c = lane + 64*i;
        xln3[(size_t)r3*384 + c] = f2b((nv[i]-mean)*rs*b2f(g3[c]) + b2f(b3[c]));
      }
    }
  } else {
    const bool isf = (*flag != 0);
    #pragma unroll
    for (int i = 0; i < 6; i++){
      const int c = lane + 64*i;
      const float ov = v[i] + up[i] + b2f(bu[c]);
      if (isf) ((float*)out)[(size_t)row*384 + c] = ov;
      else     ((bf16*)out)[(size_t)row*384 + c] = f2b(ov);
    }
  }
}

// ---------------------------------------------------------------------------
// Fused local branch v5b: direct Q/K frag global loads, reg-staged V with
// cross-chunk prefetch, __launch_bounds__(512, 2). Proven: 156us, no spill.
// ---------------------------------------------------------------------------
__global__ __launch_bounds__(512, 2) void local_kernel(
    const bf16* __restrict__ qkv3, const float* __restrict__ xres,
    const int* __restrict__ idx, const int* __restrict__ cidx,
    const bf16* __restrict__ Bp, const bf16* __restrict__ bp1,
    const bf16* __restrict__ bng, const bf16* __restrict__ bnb,
    const bf16* __restrict__ bnm, const bf16* __restrict__ bnv,
    const int* __restrict__ p_ifmm, const int* __restrict__ p_ccof,
    float* __restrict__ vis)
{
  __shared__ __align__(16) bf16 sV[3*4*64*8];  // V B-frags [h][nt][lane][8]
  __shared__ __align__(16) bf16 sP[3*2*64*8];  // P A-frags [h][mt][lane][8]
  __shared__ __align__(16) bf16 sO[3*4*64*8];  // O A-frags [h][mt*2+k0][lane][8]
  __shared__ int s_flat[32];
  __shared__ int s_tok[32];

  const int g = blockIdx.x;
  const int t = threadIdx.x, lane = t & 63, w = t >> 6;
  const int l15 = lane & 15, quad = lane >> 4;
  const int lanez = swzl(lane);                // swizzled frag-lane for LDS reads

  if (t < 32){
    const int r = idx[g*32 + t];
    s_flat[t] = r;
    s_tok[t]  = (r >> 9)*513 + 1 + (r & 511);
  }
  __syncthreads();

  // V staging geometry: 768 16B-chunks per chunk-iter; thread handles chA=t
  // (all) and chB=512+t (t<256 only).
  const int vrowA = t & 31,          vccA = t >> 5;            // 0..15
  const int vrowB = (512 + t) & 31,  vccB = (512 + t) >> 5;    // 16..23
  const int vhA = vccA >> 3, vd0A = (vccA & 7) * 8;
  const int vhB = vccB >> 3, vd0B = (vccB & 7) * 8;
  const bool hasB = (t < 256);

  uint4 svA, svB;
  {  // prefetch V(chunk 0)
    svA = *(const uint4*)(qkv3 + (size_t)s_flat[vrowA]*1152 + 768 + (0*3 + vhA)*64 + vd0A);
    if (hasB) svB = *(const uint4*)(qkv3 + (size_t)s_flat[vrowB]*1152 + 768 + (0*3 + vhB)*64 + vd0B);
  }

  f32x4 accp[3][2];
  #pragma unroll
  for (int a = 0; a < 3; a++){
    #pragma unroll
    for (int m = 0; m < 2; m++) accp[a][m] = f32x4{0.f,0.f,0.f,0.f};
  }

  #pragma unroll
  for (int hc = 0; hc < 2; hc++){
    // ---- write staged V regs -> sV (scatter-transpose, swizzled)
    {
      const bf16* sa = (const bf16*)&svA;
      #pragma unroll
      for (int j2 = 0; j2 < 8; j2++){
        const int d = vd0A + j2;
        const int L = (vrowA>>3)*16 + (d&15);
        sV[((vhA*4 + (d>>4))*64 + swzl(L))*8 + (vrowA&7)] = sa[j2];
      }
      if (hasB){
        const bf16* sb = (const bf16*)&svB;
        #pragma unroll
        for (int j2 = 0; j2 < 8; j2++){
          const int d = vd0B + j2;
          const int L = (vrowB>>3)*16 + (d&15);
          sV[((vhB*4 + (d>>4))*64 + swzl(L))*8 + (vrowB&7)] = sb[j2];
        }
      }
    }
    __syncthreads();

    // ---- phase 1: QK^T direct-from-global + softmax (waves 0..5) -> sP
    if (w < 6){
      const int h = w >> 1, mt = w & 1;
      const size_t qrow = (size_t)s_flat[mt*16 + l15]*1152;
      const int dcol = (hc*3 + h)*64 + quad*8;
      const short8 q0 = *(const short8*)(qkv3 + qrow + dcol);
      const short8 q1 = *(const short8*)(qkv3 + qrow + dcol + 32);
      f32x4 sr[2];
      #pragma unroll
      for (int nt = 0; nt < 2; nt++){
        const size_t krow = (size_t)s_flat[nt*16 + l15]*1152 + 384;
        const short8 k0 = *(const short8*)(qkv3 + krow + dcol);
        const short8 k1 = *(const short8*)(qkv3 + krow + dcol + 32);
        f32x4 acc = mfma16(q0, k0, f32x4{0.f,0.f,0.f,0.f});
        acc = mfma16(q1, k1, acc);
        #pragma unroll
        for (int r = 0; r < 4; r++) sr[nt][r] = acc[r]*0.125f;
      }
      #pragma unroll
      for (int r = 0; r < 4; r++){
        float mx = fmaxf(sr[0][r], sr[1][r]);
        #pragma unroll
        for (int mm = 8; mm; mm >>= 1) mx = fmaxf(mx, __shfl_xor(mx, mm));
        const float e0 = __expf(sr[0][r] - mx), e1 = __expf(sr[1][r] - mx);
        float sm = e0 + e1;
        #pragma unroll
        for (int mm = 8; mm; mm >>= 1) sm += __shfl_xor(sm, mm);
        const float inv = 1.f/sm;
        const int m = quad*4 + r;
        const int L0 = (l15 >> 3)*16       + m;
        const int L1 = (2 + (l15 >> 3))*16 + m;
        sP[((h*2 + mt)*64 + swzl(L0))*8 + (l15 & 7)] = f2b(e0*inv);
        sP[((h*2 + mt)*64 + swzl(L1))*8 + (l15 & 7)] = f2b(e1*inv);
      }
    }
    __syncthreads();

    // ---- phase 2: O = P V (8 waves x 3 heads) -> sO
    {
      const int mt = w & 1, nt = w >> 1;   // nt in 0..3
      const int k0w = nt >> 1, qdw = (nt & 1)*2 + (l15 >> 3), jw = l15 & 7;
      #pragma unroll
      for (int h = 0; h < 3; h++){
        const short8 a = *(const short8*)(sP + ((h*2 + mt)*64 + lanez)*8);
        const short8 b = *(const short8*)(sV + ((h*4 + nt)*64 + lanez)*8);
        const f32x4 o = mfma16(a, b, f32x4{0.f,0.f,0.f,0.f});
        #pragma unroll
        for (int r = 0; r < 4; r++){
          const int L = qdw*16 + quad*4 + r;
          sO[((h*4 + mt*2 + k0w)*64 + swzl(L))*8 + jw] = f2b(o[r]);
        }
      }
    }
    __syncthreads();

    // ---- prefetch next chunk's V (hides HBM latency under proj)
    if (hc == 0){
      svA = *(const uint4*)(qkv3 + (size_t)s_flat[vrowA]*1152 + 768 + (3 + vhA)*64 + vd0A);
      if (hasB) svB = *(const uint4*)(qkv3 + (size_t)s_flat[vrowB]*1152 + 768 + (3 + vhB)*64 + vd0B);
    }

    // ---- phase 3: proj partials accp += O_h @ Wp[hg*64:(hg+1)*64, :]
    #pragma unroll
    for (int h = 0; h < 3; h++){
      short8 afr[2][2];
      #pragma unroll
      for (int mt = 0; mt < 2; mt++){
        #pragma unroll
        for (int k0l = 0; k0l < 2; k0l++)
          afr[mt][k0l] = *(const short8*)(sO + ((h*4 + mt*2 + k0l)*64 + lanez)*8);
      }
      const int hg2 = (hc*3 + h)*2;
      #pragma unroll
      for (int tt = 0; tt < 3; tt++){
        const int nt = w*3 + tt;
        #pragma unroll
        for (int k0l = 0; k0l < 2; k0l++){
          const short8 b = *(const short8*)(Bp + ((size_t)(nt*12 + hg2 + k0l)*64 + lane)*8);
          accp[tt][0] = mfma16(afr[0][k0l], b, accp[tt][0]);
          accp[tt][1] = mfma16(afr[1][k0l], b, accp[tt][1]);
        }
      }
    }
    __syncthreads();   // protect sP/sO/sV before next chunk
  }

  // ---- epilogue: +bias +resid, pool, BN, gelu, +ccof*center
  const float fmm  = scal(p_ifmm);
  const float ccof = scal(p_ccof);
  const int cr = cidx[g];
  const int ctok = (cr >> 9)*513 + 1 + (cr & 511);
  #pragma unroll
  for (int tt = 0; tt < 3; tt++){
    const int n = (w*3 + tt)*16 + l15;
    const float bb = b2f(bp1[n]);
    float mx = -3e30f, sm = 0.f;
    #pragma unroll
    for (int mt = 0; mt < 2; mt++){
      #pragma unroll
      for (int r = 0; r < 4; r++){
        const int tok = mt*16 + quad*4 + r;
        const float v = accp[tt][mt][r] + bb + xres[(size_t)s_tok[tok]*384 + n];
        mx = fmaxf(mx, v); sm += v;
      }
    }
    mx = fmaxf(mx, __shfl_xor(mx, 16)); sm += __shfl_xor(sm, 16);
    mx = fmaxf(mx, __shfl_xor(mx, 32)); sm += __shfl_xor(sm, 32);
    if (quad == 0){
      const float lc = (fmm != 0.f) ? (mx + sm*(1.f/32.f)) : mx;
      const float nr = (lc - b2f(bnm[n])) * rsqrtf(b2f(bnv[n]) + 1e-5f) * b2f(bng[n]) + b2f(bnb[n]);
      vis[(size_t)g*384 + n] = geluf(nr) + ccof * xres[(size_t)ctok*384 + n];
    }
  }
}

// ---------------------------------------------------------------------------
// Inverse-distance interpolation v2: 4 tokens/block (was 8) -> half the
// per-block serial accumulation chain, 2x blocks (grid 128x32) for latency
// hiding. xt[b,n,:] += pro_cof * sum_s w[n,s] vis[b,s,:].
// ---------------------------------------------------------------------------
__global__ __launch_bounds__(256) void interp_kernel(const bf16* __restrict__ c1,
    const bf16* __restrict__ c2, const float* __restrict__ vis,
    const int* __restrict__ p_pcof, float* __restrict__ xres)
{
  __shared__ float s_w[4][128];
  __shared__ float s_red[2];
  const int b = blockIdx.y;
  const int n0 = blockIdx.x * 4;
  const int t = threadIdx.x;
  for (int ni = 0; ni < 4; ni++){
    const int n = n0 + ni;
    float wv = 0.f;
    if (t < 128){
      float d2 = 0.f;
      #pragma unroll
      for (int k = 0; k < 3; k++){
        const float a = b2f(c1[((size_t)b*512 + n)*3 + k]);
        const float c = b2f(c2[((size_t)b*128 + t)*3 + k]);
        const float df = a - c; d2 += df*df;
      }
      wv = 1.f/(d2 + 1e-8f);
    }
    float rsum = wv;
    #pragma unroll
    for (int mm = 32; mm; mm >>= 1) rsum += __shfl_xor(rsum, mm);
    if (((t & 63) == 0) && t < 128) s_red[t >> 6] = rsum;
    __syncthreads();
    const float tot = s_red[0] + s_red[1];
    if (t < 128) s_w[ni][t] = wv / tot;
    __syncthreads();
  }
  float acc1[4], acc2[4];
  #pragma unroll
  for (int ni = 0; ni < 4; ni++){ acc1[ni] = 0.f; acc2[ni] = 0.f; }
  for (int s = 0; s < 128; s++){
    const float* vp = vis + ((size_t)b*128 + s)*384;
    const float v1 = vp[t];
    const float v2 = (t < 128) ? vp[t + 256] : 0.f;
    #pragma unroll
    for (int ni = 0; ni < 4; ni++){
      const float wn = s_w[ni][s];
      acc1[ni] = fmaf(wn, v1, acc1[ni]);
      acc2[ni] = fmaf(wn, v2, acc2[ni]);
    }
  }
  const float pc = scal(p_pcof);
  #pragma unroll
  for (int ni = 0; ni < 4; ni++){
    const int tok = b*513 + 1 + n0 + ni;
    xres[(size_t)tok*384 + t] += pc*acc1[ni];
    if (t < 128) xres[(size_t)tok*384 + t + 256] += pc*acc2[ni];
  }
}

// ---------------------------------------------------------------------------
extern "C" void kernel_launch(void* const* d_in, const int* in_sizes, int n_in,
                              void* d_out, int out_size, void* d_ws, size_t ws_size,
                              hipStream_t stream)
{
  (void)n_in; (void)out_size; (void)ws_size;
  const int*  idx   = (const int*)d_in[35];
  const int*  cidx  = (const int*)d_in[36];
  const int*  ifmm  = (const int*)d_in[38];
  const int*  pcof  = (const int*)d_in[39];
  const int*  ccof  = (const int*)d_in[40];

  size_t off = 0;
  auto alloc = [&](size_t bytes) -> void* {
    void* p = (char*)d_ws + off; off += (bytes + 255) & ~(size_t)255; return p;
  };
  int*   flag = (int*)  alloc(sizeof(int));
  float* xres = (float*)alloc((size_t)TOK*384*4);
  bf16*  slab = (bf16*) alloc((size_t)TOK*1536*2);
  bf16*  xn   = (bf16*) alloc((size_t)TOK*384*2);
  float* pq   = (float*)alloc((size_t)10*1152*4);
  bf16*  Bq   = (bf16*) alloc((size_t)72*12*64*8*2);   // shuffled a1_Wqkv
  bf16*  Bp   = (bf16*) alloc((size_t)24*12*64*8*2);   // shuffled a1_Wproj
  bf16*  Bqkv = (bf16*) alloc((size_t)72*12*64*8*2);   // shuffled Wqkv
  bf16*  Bw1  = (bf16*) alloc((size_t)96*12*64*8*2);   // shuffled W1
  bf16*  Bw2  = (bf16*) alloc((size_t)24*48*64*8*2);   // shuffled W2
  bf16*  Bwp  = (bf16*) alloc((size_t)24*12*64*8*2);   // shuffled Wproj

  // slab overlays (time-phased):
  //   A: qkvb [0, TOK*1152) + canonical-x [TOK*1152, TOK*1536)
  //   B: h1   [0, TOK*1536)
  //   C: qkv3 [0, 16384*1152) + xln3 [TOK*1152, +16384*384)
  bf16*  qkvb = slab;
  bf16*  x_c  = slab + (size_t)TOK*1152;
  bf16*  h1   = slab;
  bf16*  qkv3 = slab;
  bf16*  xln3 = slab + (size_t)TOK*1152;
  bf16*  ao   = xn;
  bf16*  hbuf = xn;
  float* visb = (float*)xn;   // vis (6.3 MB) overlays xn after h is consumed

  const int conv_ids[34] = {0,1,2,4,5,6,7,8,9,10,11,12,13,14,15,16,17,
                            18,19,20,21,22,23,24,25,26,27,28,29,30,31,32,33,34};
  ConvArgs ca;
  bf16* canon[41];
  int maxn = 1;
  for (int k = 0; k < 34; k++){
    const int i = conv_ids[k];
    const int n = in_sizes[i];
    bf16* dst = (i == 0) ? x_c : (bf16*)alloc((size_t)n*2);
    ca.src[k] = d_in[i]; ca.dst[k] = dst; ca.n[k] = n;
    canon[i] = dst;
    if (n > maxn) maxn = n;
  }
  detect_kernel<<<dim3(1), dim3(256), 0, stream>>>((const unsigned*)d_in[0], flag);
  {
    int gx = (maxn/8 + 255) / 256; if (gx > 512) gx = 512; if (gx < 1) gx = 1;
    convert_many<<<dim3(gx, 34), dim3(256), 0, stream>>>(flag, ca);
  }

  const bf16 *x_in = canon[0], *c1 = canon[1], *c2 = canon[2], *pe = canon[4],
             *ln1g = canon[5], *ln1b = canon[6], *Wqkv = canon[7], *Wproj = canon[8],
             *bproj = canon[9], *gate = canon[10], *ln2g = canon[11], *ln2b = canon[12],
             *W1 = canon[13], *b1 = canon[14], *W2 = canon[15], *b2v = canon[16],
             *adW = canon[17], *adb = canon[18], *adU = canon[19], *adub = canon[20],
             *adg = canon[21], *bng = canon[22], *bnb = canon[23], *bnm = canon[24],
             *bnv = canon[25], *ln3g = canon[26], *ln3b = canon[27], *a1W = canon[28],
             *a1P = canon[29], *a1pb = canon[30], *d1W = canon[31], *d1b = canon[32],
             *u1W = canon[33], *u1b = canon[34];

  // weight shuffles: all 6 in ONE dispatch (blockIdx.y selects weight)
  {
    ShufArgs sa;
    sa.W[0]=a1W;   sa.out[0]=Bq;   sa.N[0]=1152; sa.KT[0]=12; sa.NT[0]=72;
    sa.W[1]=a1P;   sa.out[1]=Bp;   sa.N[1]=384;  sa.KT[1]=12; sa.NT[1]=24;
    sa.W[2]=Wqkv;  sa.out[2]=Bqkv; sa.N[2]=1152; sa.KT[2]=12; sa.NT[2]=72;
    sa.W[3]=W1;    sa.out[3]=Bw1;  sa.N[3]=1536; sa.KT[3]=12; sa.NT[3]=96;
    sa.W[4]=W2;    sa.out[4]=Bw2;  sa.N[4]=384;  sa.KT[4]=48; sa.NT[4]=24;
    sa.W[5]=Wproj; sa.out[5]=Bwp;  sa.N[5]=384;  sa.KT[5]=12; sa.NT[5]=24;
    shuffle_many<<<dim3(288, 6), dim3(256), 0, stream>>>(sa);
  }

  // 1. LN1
  ln_kernel<true><<<dim3((TOK*64)/256), dim3(256), 0, stream>>>((const void*)x_in, ln1g, ln1b, xn, TOK);
  // 2. qkv = xn @ Wqkv (MFMA 128x128, async A-staging)
  mfma_gemm<1><<<dim3(9,129), dim3(256), 0, stream>>>(xn, Bqkv, nullptr, nullptr, qkvb, TOK, 1152, 384);
  // 2b. prompt qkv
  pqkv_kernel<<<dim3(18), dim3(256), 0, stream>>>(pe, Wqkv, pq);
  // 3. attention v4b (async dbuf K, reg-prefetched V, Q in regs) -> ao
  attn_kernel<<<dim3(9,192), dim3(256), 0, stream>>>(qkvb, pq, gate, ao);
  // 4. xres = x + ao @ Wproj + bproj
  mfma_gemm<3><<<dim3(3,129), dim3(256), 0, stream>>>(ao, Bwp, bproj, x_in, xres, TOK, 384, 384);
  // 5. LN2
  ln_kernel<false><<<dim3((TOK*64)/256), dim3(256), 0, stream>>>((const void*)xres, ln2g, ln2b, xn, TOK);
  // 6. h1 = gelu(xn @ W1 + b1)
  mfma_gemm<2><<<dim3(12,129), dim3(256), 0, stream>>>(xn, Bw1, b1, nullptr, h1, TOK, 1536, 384);
  // 7. h = h1 @ W2 + b2
  mfma_gemm<0><<<dim3(3,129), dim3(256), 0, stream>>>(h1, Bw2, b2v, nullptr, hbuf, TOK, 384, 1536);
  // 8. adapter mid (wave-per-row, fused LN3 -> xln3)
  adapter_kernel<true><<<dim3(TOK/4), dim3(256), 0, stream>>>(
      (const void*)hbuf, adW, adb, adU, adub, adg, ln3g, ln3b, nullptr, xres, xln3, nullptr);
  // 8c. qkv3 = xln3 @ a1_Wqkv (deduped, flat MFMA GEMM)
  mfma_gemm<1><<<dim3(9,128), dim3(256), 0, stream>>>(xln3, Bq, nullptr, nullptr, qkv3, 16384, 1152, 384);
  // 9. local branch v5b (direct Q/K frag loads, reg-staged V) -> vis
  local_kernel<<<dim3(4096), dim3(512), 0, stream>>>(qkv3, xres, idx, cidx, Bp, a1pb,
                                                     bng, bnb, bnm, bnv, ifmm, ccof, visb);
  // 10. interp v2 (4 tokens/block, 2x blocks)
  interp_kernel<<<dim3(128,32), dim3(256), 0, stream>>>(c1, c2, visb, pcof, xres);
  // 11. final adapter (wave-per-row) -> d_out (dtype per flag)
  adapter_kernel<false><<<dim3(TOK/4), dim3(256), 0, stream>>>(
      (const void*)xres, d1W, d1b, u1W, u1b, nullptr, nullptr, nullptr, flag, nullptr, nullptr, d_out);
}